// Round 1
// baseline (1180.910 us; speedup 1.0000x reference)
//
#include <hip/hip_runtime.h>
#include <stdint.h>

#define NVOX 500000

typedef float  f32x4  __attribute__((ext_vector_type(4)));
typedef short  short8 __attribute__((ext_vector_type(8)));

__device__ __forceinline__ short f2bf(float x){
  unsigned u = __float_as_uint(x);
  unsigned r = (u + 0x7fffu + ((u >> 16) & 1u)) >> 16;   // RNE truncate to bf16
  return (short)r;
}

__device__ __forceinline__ void gload_lds16(const void* g, void* l){
  __builtin_amdgcn_global_load_lds(
      (const __attribute__((address_space(1))) unsigned int*)(uintptr_t)g,
      (__attribute__((address_space(3))) unsigned int*)(unsigned int)(uintptr_t)l,
      16, 0, 0);
}

// ---------------- prep: feats fp32 -> bf16 table ----------------
__global__ void cast_feats_kernel(const float* __restrict__ f, short* __restrict__ t){
  long i = ((long)blockIdx.x * 256 + threadIdx.x) * 8;   // 64e6 elems, exact grid
  float4 a = *(const float4*)(f + i);
  float4 b = *(const float4*)(f + i + 4);
  short8 o = { f2bf(a.x), f2bf(a.y), f2bf(a.z), f2bf(a.w),
               f2bf(b.x), f2bf(b.y), f2bf(b.z), f2bf(b.w) };
  *(short8*)(t + i) = o;
}

// ---------------- prep: weights -> bf16, MFMA-B fragment order ----------------
// B-frag (16x16x32): lane l holds B[k = ks*32 + (l>>4)*8 + j][col = nf*16 + (l&15)]
// layouts: cw_sw[k27][nf8][ks4][lane64][8]; w1_sw[nf32][ks4][lane][8];
//          w2_sw[hc4][nf8][ks4][lane][8]  (hc = K-chunk of 128 in the 512-K GEMM2)
__global__ void prep_weights_kernel(const float* __restrict__ cw, const float* __restrict__ w1,
                                    const float* __restrict__ w2,
                                    short* __restrict__ cw_sw, short* __restrict__ w1_sw,
                                    short* __restrict__ w2_sw){
  int t = blockIdx.x * 256 + threadIdx.x;    // 71680 total, exact grid
  if (t < 55296){
    int k = t >> 11, rem = t & 2047;
    int nf = rem >> 8, ks = (rem >> 6) & 3, l = rem & 63;
    int g = l >> 4, c = l & 15;
    short8 o;
    #pragma unroll
    for (int j = 0; j < 8; j++){
      int kk = ks*32 + g*8 + j;
      o[j] = f2bf(cw[(k*128 + kk)*128 + nf*16 + c]);
    }
    *(short8*)(cw_sw + (size_t)t*8) = o;
  } else if (t < 63488){
    int u = t - 55296;
    int nf = u >> 8, ks = (u >> 6) & 3, l = u & 63;
    int g = l >> 4, c = l & 15;
    short8 o;
    #pragma unroll
    for (int j = 0; j < 8; j++){
      int kk = ks*32 + g*8 + j;
      o[j] = f2bf(w1[kk*512 + nf*16 + c]);   // w1 [128][512]
    }
    *(short8*)(w1_sw + (size_t)u*8) = o;
  } else {
    int u = t - 63488;
    int hc = u >> 11, nf = (u >> 8) & 7, ks = (u >> 6) & 3, l = u & 63;
    int g = l >> 4, c = l & 15;
    short8 o;
    #pragma unroll
    for (int j = 0; j < 8; j++){
      int h = (hc*4 + ks)*32 + g*8 + j;
      o[j] = f2bf(w2[h*128 + nf*16 + c]);    // w2 [512][128]
    }
    *(short8*)(w2_sw + (size_t)u*8) = o;
  }
}

// ---------------- fused sparse conv (27 offsets) + LayerNorm -> hn bf16 ----------------
// block: 256 thr = 4 waves; tile 256 rows x 128 cols; wave = 64 rows (4 mf x 8 nf)
template<bool TBL>
__global__ __launch_bounds__(256, 2)
void conv_ln_kernel(const short* __restrict__ table, const float* __restrict__ feats,
                    const int* __restrict__ nbr, const short* __restrict__ cw_sw,
                    const float* __restrict__ conv_b, const float* __restrict__ ln_g,
                    const float* __restrict__ ln_b, short* __restrict__ hn16){
  __shared__ __align__(16) short lds_b[2][16384];   // 2 x 32KB double-buffered B stage
  const int tid = threadIdx.x;
  const int lane = tid & 63, wv = tid >> 6;
  const int l15 = lane & 15, lg = lane >> 4;
  const int rowbase = blockIdx.x * 256 + wv * 64;

  f32x4 acc[4][8];
  #pragma unroll
  for (int m = 0; m < 4; m++)
    #pragma unroll
    for (int n = 0; n < 8; n++)
      acc[m][n] = f32x4{0.f, 0.f, 0.f, 0.f};

  { // stage offset 0 -> buf 0
    const char* src = (const char*)cw_sw;
    char* dst = (char*)&lds_b[0][0];
    #pragma unroll
    for (int i = 0; i < 8; i++){ int off = i*4096 + tid*16; gload_lds16(src+off, dst+off); }
  }

  for (int k = 0; k < 27; k++){
    const int buf = k & 1;
    __syncthreads();          // drains vmcnt(0): stage k complete; prev ds_reads done
    if (k + 1 < 27){          // prefetch next offset's B while computing this one
      const char* src = (const char*)cw_sw + (size_t)(k+1)*32768;
      char* dst = (char*)&lds_b[buf ^ 1][0];
      #pragma unroll
      for (int i = 0; i < 8; i++){ int off = i*4096 + tid*16; gload_lds16(src+off, dst+off); }
    }
    int idxr[4];
    #pragma unroll
    for (int m = 0; m < 4; m++){
      int row = rowbase + m*16 + l15;
      row = row < NVOX ? row : NVOX - 1;
      int id = nbr[row*27 + k];
      idxr[m] = TBL ? (id < 0 ? NVOX : id) : id;
    }
    const short* bbase = &lds_b[buf][0];
    #pragma unroll
    for (int ks = 0; ks < 4; ks++){
      short8 af[4];
      #pragma unroll
      for (int m = 0; m < 4; m++){
        if constexpr (TBL){
          af[m] = *(const short8*)(table + (size_t)idxr[m]*128 + ks*32 + lg*8);
        } else {
          if (idxr[m] < 0){
            af[m] = short8{0,0,0,0,0,0,0,0};
          } else {
            const float* p = feats + (size_t)idxr[m]*128 + ks*32 + lg*8;
            float4 x = *(const float4*)p;
            float4 y = *(const float4*)(p + 4);
            af[m] = short8{ f2bf(x.x), f2bf(x.y), f2bf(x.z), f2bf(x.w),
                            f2bf(y.x), f2bf(y.y), f2bf(y.z), f2bf(y.w) };
          }
        }
      }
      #pragma unroll
      for (int n = 0; n < 8; n++){
        short8 b = *(const short8*)(bbase + ((n*4 + ks)*64 + lane)*8);
        #pragma unroll
        for (int m = 0; m < 4; m++)
          acc[m][n] = __builtin_amdgcn_mfma_f32_16x16x32_bf16(af[m], b, acc[m][n], 0, 0, 0);
      }
    }
  }

  // epilogue: +conv_b, LayerNorm (fp32), -> bf16
  float cb[8], g8[8], be[8];
  #pragma unroll
  for (int n = 0; n < 8; n++){
    cb[n] = conv_b[n*16 + l15];
    g8[n] = ln_g[n*16 + l15];
    be[n] = ln_b[n*16 + l15];
  }
  #pragma unroll
  for (int m = 0; m < 4; m++){
    #pragma unroll
    for (int r = 0; r < 4; r++){
      float s = 0.f, s2 = 0.f;
      #pragma unroll
      for (int n = 0; n < 8; n++){
        float h = acc[m][n][r] + cb[n];
        acc[m][n][r] = h;
        s += h; s2 += h*h;
      }
      #pragma unroll
      for (int msk = 1; msk < 16; msk <<= 1){   // reduce across the 16 lanes holding this row
        s  += __shfl_xor(s,  msk);
        s2 += __shfl_xor(s2, msk);
      }
      float mu  = s  * 0.0078125f;
      float var = s2 * 0.0078125f - mu*mu;
      float rs  = rsqrtf(var + 1e-6f);
      int row = rowbase + m*16 + lg*4 + r;
      if (row < NVOX){
        #pragma unroll
        for (int n = 0; n < 8; n++){
          float hv = (acc[m][n][r] - mu) * rs * g8[n] + be[n];
          hn16[(size_t)row*128 + n*16 + l15] = f2bf(hv);
        }
      }
    }
  }
}

// ---------------- fused MLP: silu(hn@w1+b1)@w2 + b2 + feats ----------------
// block 256 thr = 4 waves; tile 128 rows; wave = 32 rows (2 mf x 8 nf)
// HID chunked by 128: GEMM1 chunk -> silu -> LDS act (XOR-swizzled) -> GEMM2 partial
__global__ __launch_bounds__(256, 2)
void mlp_kernel(const short* __restrict__ hn16, const float* __restrict__ feats,
                const short* __restrict__ w1_sw, const short* __restrict__ w2_sw,
                const float* __restrict__ b1, const float* __restrict__ b2,
                float* __restrict__ out){
  __shared__ __align__(16) short lds_w[16384];        // 32KB weight stage (w1c / w2c)
  __shared__ __align__(16) short lds_act[4*4096];     // 4 waves x 32rows x 128 bf16
  const int tid = threadIdx.x;
  const int lane = tid & 63, wv = tid >> 6;
  const int l15 = lane & 15, lg = lane >> 4;
  const int rowbase = blockIdx.x * 128 + wv * 32;
  short* actw = &lds_act[wv * 4096];

  f32x4 acc2[2][8];
  #pragma unroll
  for (int m = 0; m < 2; m++)
    #pragma unroll
    for (int n = 0; n < 8; n++)
      acc2[m][n] = f32x4{0.f, 0.f, 0.f, 0.f};

  float bb2[8];
  #pragma unroll
  for (int n = 0; n < 8; n++) bb2[n] = b2[n*16 + l15];

  for (int hc = 0; hc < 4; hc++){
    __syncthreads();                       // prev GEMM2 reads of lds_w done
    { const char* src = (const char*)w1_sw + (size_t)hc*32768;
      char* dst = (char*)lds_w;
      #pragma unroll
      for (int i = 0; i < 8; i++){ int off = i*4096 + tid*16; gload_lds16(src+off, dst+off); } }
    __syncthreads();                       // stage complete (vmcnt drained)

    float bb1[8];
    #pragma unroll
    for (int n = 0; n < 8; n++) bb1[n] = b1[hc*128 + n*16 + l15];

    f32x4 acc1[2][8];
    #pragma unroll
    for (int m = 0; m < 2; m++)
      #pragma unroll
      for (int n = 0; n < 8; n++)
        acc1[m][n] = f32x4{0.f, 0.f, 0.f, 0.f};

    #pragma unroll
    for (int ks = 0; ks < 4; ks++){
      short8 a1[2];
      #pragma unroll
      for (int m = 0; m < 2; m++){
        int row = rowbase + m*16 + l15;
        row = row < NVOX ? row : NVOX - 1;
        a1[m] = *(const short8*)(hn16 + (size_t)row*128 + ks*32 + lg*8);
      }
      #pragma unroll
      for (int n = 0; n < 8; n++){
        short8 b = *(const short8*)(lds_w + ((n*4 + ks)*64 + lane)*8);
        #pragma unroll
        for (int m = 0; m < 2; m++)
          acc1[m][n] = __builtin_amdgcn_mfma_f32_16x16x32_bf16(a1[m], b, acc1[m][n], 0, 0, 0);
      }
    }

    // SiLU -> act tile (swizzled row-major, b16 stores; D-frag: row=(lg*4+r), col=(n*16+l15))
    #pragma unroll
    for (int m = 0; m < 2; m++)
      #pragma unroll
      for (int n = 0; n < 8; n++)
        #pragma unroll
        for (int r = 0; r < 4; r++){
          float x  = acc1[m][n][r] + bb1[n];
          float sg = x / (1.f + __expf(-x));
          int rowloc = m*16 + lg*4 + r;
          int col    = n*16 + l15;
          actw[(rowloc*128 + col) ^ ((rowloc & 7) << 3)] = f2bf(sg);
        }

    __syncthreads();                       // act writes + GEMM1 lds_w reads drained
    { const char* src = (const char*)w2_sw + (size_t)hc*32768;
      char* dst = (char*)lds_w;
      #pragma unroll
      for (int i = 0; i < 8; i++){ int off = i*4096 + tid*16; gload_lds16(src+off, dst+off); } }
    __syncthreads();

    #pragma unroll
    for (int ks2 = 0; ks2 < 4; ks2++){
      short8 a2[2];
      #pragma unroll
      for (int m = 0; m < 2; m++){
        int rowloc = m*16 + l15;           // A-frag: row=l&15, k=(lg*8+j)
        a2[m] = *(const short8*)(actw + ((rowloc*128 + ks2*32 + lg*8) ^ ((rowloc & 7) << 3)));
      }
      #pragma unroll
      for (int n = 0; n < 8; n++){
        short8 b = *(const short8*)(lds_w + ((n*4 + ks2)*64 + lane)*8);
        #pragma unroll
        for (int m = 0; m < 2; m++)
          acc2[m][n] = __builtin_amdgcn_mfma_f32_16x16x32_bf16(a2[m], b, acc2[m][n], 0, 0, 0);
      }
    }
  }

  // epilogue: + b2 + residual feats (fp32), store fp32
  #pragma unroll
  for (int m = 0; m < 2; m++)
    #pragma unroll
    for (int n = 0; n < 8; n++)
      #pragma unroll
      for (int r = 0; r < 4; r++){
        int row = rowbase + m*16 + lg*4 + r;
        if (row < NVOX){
          size_t ci = (size_t)row*128 + n*16 + l15;
          out[ci] = acc2[m][n][r] + bb2[n] + feats[ci];
        }
      }
}

extern "C" void kernel_launch(void* const* d_in, const int* in_sizes, int n_in,
                              void* d_out, int out_size, void* d_ws, size_t ws_size,
                              hipStream_t stream){
  const float* feats = (const float*)d_in[0];
  const int*   nbr   = (const int*)  d_in[1];
  const float* cw    = (const float*)d_in[2];
  const float* cb    = (const float*)d_in[3];
  const float* lng   = (const float*)d_in[4];
  const float* lnb   = (const float*)d_in[5];
  const float* w1    = (const float*)d_in[6];
  const float* b1    = (const float*)d_in[7];
  const float* w2    = (const float*)d_in[8];
  const float* b2    = (const float*)d_in[9];
  float* out = (float*)d_out;

  char* ws = (char*)d_ws;
  const size_t TABLE_B = (size_t)(NVOX + 1) * 256;   // 128,000,256
  const size_t HN_B    = (size_t)NVOX * 256;         // 128,000,000
  const size_t CW_B    = 55296u * 16u;               // 884,736
  const size_t W1_B    = 8192u * 16u;                // 131,072
  const size_t W2_B    = 8192u * 16u;
  const size_t need_full = TABLE_B + HN_B + CW_B + W1_B + W2_B;

  if (ws_size >= need_full){
    short* table = (short*)ws;
    short* hn16  = (short*)(ws + TABLE_B);
    short* cw_sw = (short*)(ws + TABLE_B + HN_B);
    short* w1_sw = (short*)(ws + TABLE_B + HN_B + CW_B);
    short* w2_sw = (short*)(ws + TABLE_B + HN_B + CW_B + W1_B);

    cast_feats_kernel<<<31250, 256, 0, stream>>>(feats, table);
    hipMemsetAsync((void*)(table + (size_t)NVOX * 128), 0, 256, stream);  // zero row
    prep_weights_kernel<<<280, 256, 0, stream>>>(cw, w1, w2, cw_sw, w1_sw, w2_sw);
    conv_ln_kernel<true><<<1954, 256, 0, stream>>>(table, feats, nbr, cw_sw, cb, lng, lnb, hn16);
    mlp_kernel<<<3907, 256, 0, stream>>>(hn16, feats, w1_sw, w2_sw, b1, b2, out);
  } else {
    // slim path: no bf16 table; gather fp32 feats directly (zero-fill missing)
    short* hn16  = (short*)ws;
    short* cw_sw = (short*)(ws + HN_B);
    short* w1_sw = (short*)(ws + HN_B + CW_B);
    short* w2_sw = (short*)(ws + HN_B + CW_B + W1_B);

    prep_weights_kernel<<<280, 256, 0, stream>>>(cw, w1, w2, cw_sw, w1_sw, w2_sw);
    conv_ln_kernel<false><<<1954, 256, 0, stream>>>(nullptr, feats, nbr, cw_sw, cb, lng, lnb, hn16);
    mlp_kernel<<<3907, 256, 0, stream>>>(hn16, feats, w1_sw, w2_sw, b1, b2, out);
  }
}